// Round 5
// baseline (196.089 us; speedup 1.0000x reference)
//
#include <hip/hip_runtime.h>
#include <hip/hip_bf16.h>
#include <math.h>

// Top2Router: x[4,4096,2048] fp32, W[8,2048] fp32, b[8] fp32
//   logits = x @ W^T + b ; gate = softmax(logits, -1) ; top2 of gate
// d_out (fp32, concat): [0,32768) top2_val | [32768,65536) top2_idx |
//                       [65536,196608) gate
//
// R5: bulk-staged, double-buffered x through LDS.
//   - R2-R4 all pinned at ~59us: effectively 1 load in flight/wave, and the
//     compute-shaped access pattern (8 x 128B scattered segments per wave-load,
//     revisited ~2200cyc apart) gives the memory system zero burst locality.
//   - Now: fetch shape != compute shape. Per k-tile (KT=128 floats) each block
//     stages 64 tokens x 512B = 32KB with lane-contiguous float4 loads
//     (2 token-chunks of 512B per wave-load), all issued back-to-back ->
//     32KB in flight per CU. Compute reads x+W from LDS only (lgkmcnt domain),
//     so tile t's compute overlaps tile t+1's global flight; vmcnt drains at
//     the ds_write+barrier AFTER compute.
//   - W (64KB) staged once; x dbuf 2x32KB -> 128KB LDS, 1 block/CU, 4 waves.
//   - Compute keeps the verified A=16 structure (lane = st*8+j, T=2 tokens).

#define NTOK  16384
#define DM    2048
#define NE    8
#define KT    128           // k-tile in floats (512 B per token)
#define NTILE (DM / KT)     // 16
#define TPB   64            // tokens per block

__device__ __forceinline__ float fold4(const float4 a) {
    return (a.x + a.y) + (a.z + a.w);
}

// Reduce-scatter 8 per-lane expert partials across the 8 j-lanes of a token:
// returns the full dot for expert e == j. (Verified R2-R4.)
__device__ __forceinline__ float reduce_scatter8(const float4* acc, const int j) {
    float v0 = fold4(acc[0]), v1 = fold4(acc[1]), v2 = fold4(acc[2]), v3 = fold4(acc[3]);
    float v4 = fold4(acc[4]), v5 = fold4(acc[5]), v6 = fold4(acc[6]), v7 = fold4(acc[7]);
    float s0 = v0 + __shfl_xor(v0, 1, 8);
    float s1 = v1 + __shfl_xor(v1, 1, 8);
    float s2 = v2 + __shfl_xor(v2, 1, 8);
    float s3 = v3 + __shfl_xor(v3, 1, 8);
    float s4 = v4 + __shfl_xor(v4, 1, 8);
    float s5 = v5 + __shfl_xor(v5, 1, 8);
    float s6 = v6 + __shfl_xor(v6, 1, 8);
    float s7 = v7 + __shfl_xor(v7, 1, 8);
    const bool b0 = (j & 1);
    float t0 = b0 ? s1 : s0;
    float t1 = b0 ? s3 : s2;
    float t2 = b0 ? s5 : s4;
    float t3 = b0 ? s7 : s6;
    float p0 = t0 + __shfl_xor(t0, 2, 8);
    float p1 = t1 + __shfl_xor(t1, 2, 8);
    float p2 = t2 + __shfl_xor(t2, 2, 8);
    float p3 = t3 + __shfl_xor(t3, 2, 8);
    const bool b1 = (j & 2);
    float u0 = b1 ? p1 : p0;
    float u1 = b1 ? p3 : p2;
    float q0 = u0 + __shfl_xor(u0, 4, 8);
    float q1 = u1 + __shfl_xor(u1, 4, 8);
    return (j & 4) ? q1 : q0;
}

// 8-lane softmax + top2 epilogue for one token. (Verified R1-R4.)
__device__ __forceinline__ void softmax_top2(const float logit, const int j,
                                             const int token, float* __restrict__ out) {
    float m = logit;
#pragma unroll
    for (int s = 4; s; s >>= 1) m = fmaxf(m, __shfl_xor(m, s, 8));
    const float ex = expf(logit - m);
    float sum = ex;
#pragma unroll
    for (int s = 4; s; s >>= 1) sum += __shfl_xor(sum, s, 8);
    const float gate = ex / sum;

    out[65536 + token * NE + j] = gate;

    float g1 = gate; int e1 = j;
#pragma unroll
    for (int s = 4; s; s >>= 1) {
        const float og = __shfl_xor(g1, s, 8);
        const int   oe = __shfl_xor(e1, s, 8);
        if (og > g1 || (og == g1 && oe < e1)) { g1 = og; e1 = oe; }
    }
    float g2 = (j == e1) ? -INFINITY : gate; int e2 = j;
#pragma unroll
    for (int s = 4; s; s >>= 1) {
        const float og = __shfl_xor(g2, s, 8);
        const int   oe = __shfl_xor(e2, s, 8);
        if (og > g2 || (og == g2 && oe < e2)) { g2 = og; e2 = oe; }
    }
    if (j == 0) {
        out[token * 2 + 0]         = g1;
        out[token * 2 + 1]         = g2;
        out[32768 + token * 2 + 0] = (float)e1;
        out[32768 + token * 2 + 1] = (float)e2;
    }
}

__global__ __launch_bounds__(256, 1) void top2router_kernel(
    const float* __restrict__ x,
    const float* __restrict__ W,
    const float* __restrict__ b,
    float* __restrict__ out)
{
    __shared__ __align__(16) float sW[NE * DM];       // 64 KB, resident all kernel
    __shared__ __align__(16) float sX[2][TPB * KT];   // 2 x 32 KB double buffer

    const int t    = threadIdx.x;
    const int lane = t & 63;
    const int wave = t >> 6;
    const int j    = lane & 7;     // d-slice id == expert id after reduce-scatter
    const int st   = lane >> 3;    // sub-token 0..7
    const int blk  = blockIdx.x;

    const int half = lane >> 5;    // staging: which token of the chunk-pair
    const int hl   = lane & 31;    // staging: lane within the 512B token chunk

    // ---- stage all of W into LDS (flat copy: 4096 float4 / 256 threads) ----
    {
        const float4* __restrict__ Wv = reinterpret_cast<const float4*>(W);
        float4* sWv = reinterpret_cast<float4*>(sW);
#pragma unroll
        for (int i = 0; i < 16; ++i)
            sWv[i * 256 + t] = Wv[i * 256 + t];
    }

    // ---- stage x tile 0 into sX[0] ----
    // chunk c = wave*8 + i covers tokens {2c, 2c+1}; each half-wave loads a
    // contiguous 512B token chunk (32 lanes x 16B).
#pragma unroll
    for (int i = 0; i < 8; ++i) {
        const int c   = wave * 8 + i;
        const int tok = 2 * c + half;
        const float4 v = *reinterpret_cast<const float4*>(
            x + (size_t)(blk * TPB + tok) * DM + hl * 4);
        *reinterpret_cast<float4*>(&sX[0][tok * KT + hl * 4]) = v;
    }
    __syncthreads();

    const int t0    = wave * 16 + st;        // block-local token ids
    const int t1    = t0 + 8;
    const int gtok0 = blk * TPB + t0;
    const int gtok1 = blk * TPB + t1;

    float4 acc0[NE], acc1[NE];
#pragma unroll
    for (int e = 0; e < NE; ++e) {
        acc0[e] = make_float4(0.f, 0.f, 0.f, 0.f);
        acc1[e] = make_float4(0.f, 0.f, 0.f, 0.f);
    }

    int cur = 0;
    for (int tl = 0; tl < NTILE; ++tl) {
        // 1) issue next tile's global loads (no use yet -> stay in flight)
        float4 r[8];
        if (tl + 1 < NTILE) {
#pragma unroll
            for (int i = 0; i < 8; ++i) {
                const int c   = wave * 8 + i;
                const int tok = 2 * c + half;
                r[i] = *reinterpret_cast<const float4*>(
                    x + (size_t)(blk * TPB + tok) * DM + (tl + 1) * KT + hl * 4);
            }
        }

        // 2) compute tile tl entirely from LDS (lgkmcnt domain only)
#pragma unroll
        for (int k2 = 0; k2 < KT / 32; ++k2) {     // 4 iters
            const int xo = k2 * 32 + j * 4;
            const float4 xv0 = *reinterpret_cast<const float4*>(&sX[cur][t0 * KT + xo]);
            const float4 xv1 = *reinterpret_cast<const float4*>(&sX[cur][t1 * KT + xo]);
            const int wo = tl * KT + xo;
#pragma unroll
            for (int e = 0; e < NE; ++e) {
                const float4 wv = *reinterpret_cast<const float4*>(&sW[e * DM + wo]);
                acc0[e].x = fmaf(xv0.x, wv.x, acc0[e].x);
                acc0[e].y = fmaf(xv0.y, wv.y, acc0[e].y);
                acc0[e].z = fmaf(xv0.z, wv.z, acc0[e].z);
                acc0[e].w = fmaf(xv0.w, wv.w, acc0[e].w);
                acc1[e].x = fmaf(xv1.x, wv.x, acc1[e].x);
                acc1[e].y = fmaf(xv1.y, wv.y, acc1[e].y);
                acc1[e].z = fmaf(xv1.z, wv.z, acc1[e].z);
                acc1[e].w = fmaf(xv1.w, wv.w, acc1[e].w);
            }
        }

        // 3) deposit next tile into the other buffer (vmcnt waits land HERE,
        //    after compute), then barrier
        if (tl + 1 < NTILE) {
#pragma unroll
            for (int i = 0; i < 8; ++i) {
                const int c   = wave * 8 + i;
                const int tok = 2 * c + half;
                *reinterpret_cast<float4*>(&sX[cur ^ 1][tok * KT + hl * 4]) = r[i];
            }
        }
        __syncthreads();
        cur ^= 1;
    }

    const float logit0 = reduce_scatter8(acc0, j) + b[j];
    const float logit1 = reduce_scatter8(acc1, j) + b[j];

    softmax_top2(logit0, j, gtok0, out);
    softmax_top2(logit1, j, gtok1, out);
}

extern "C" void kernel_launch(void* const* d_in, const int* in_sizes, int n_in,
                              void* d_out, int out_size, void* d_ws, size_t ws_size,
                              hipStream_t stream) {
    const float* x = (const float*)d_in[0];
    const float* W = (const float*)d_in[1];
    const float* b = (const float*)d_in[2];
    float* out = (float*)d_out;

    // 64 tokens/block, 256 blocks = 1 block/CU (128 KB LDS caps at 1 anyway).
    top2router_kernel<<<NTOK / TPB, 256, 0, stream>>>(x, W, b, out);
}

// Round 6
// 193.429 us; speedup vs baseline: 1.0138x; 1.0138x over previous
//
#include <hip/hip_runtime.h>
#include <hip/hip_bf16.h>
#include <math.h>

// Top2Router: x[4,4096,2048] fp32, W[8,2048] fp32, b[8] fp32
//   logits = x @ W^T + b ; gate = softmax(logits, -1) ; top2 of gate
// d_out (fp32, concat): [0,32768) top2_val | [32768,65536) top2_idx |
//                       [65536,196608) gate
//
// R6: split-K for occupancy. R2-R5 all pinned at ~60us: one barrier-locked
// 64KB-W workgroup per CU -> <=8 waves/CU breathing in phase -> memory queue
// duty cycle ~35% (2.2 TB/s). Fix the STRUCTURAL constraint (W LDS footprint):
//   K1: 4096 blocks = 512 token-chunks x 8 k-slices. Each block stages an
//       8KB W-slice, computes 32 tokens' partial dots over 256 d-floats,
//       writes deterministic partials to d_ws[ks][tok*8+e] (4MB, no atomics).
//       6 blocks/CU resident -> 24 decorrelated waves/CU, depth-2 prefetch
//       -> ~48KB sustained in flight per CU -> HBM-saturating via TLP.
//   K2: 512 blocks sum the 8 partials, add b, verified softmax/top2 epilogue.

#define NTOK  16384
#define DM    2048
#define NE    8
#define KS    8              // k-slices
#define KSF   (DM / KS)      // 256 floats per slice
#define PART_STRIDE (NTOK * NE)   // 131072 floats per slice plane

__device__ __forceinline__ float fold4(const float4 a) {
    return (a.x + a.y) + (a.z + a.w);
}

// Reduce-scatter 8 per-lane expert partials across the 8 j-lanes of a token:
// returns the dot for expert e == j. (Verified R2-R5.)
__device__ __forceinline__ float reduce_scatter8(const float4* acc, const int j) {
    float v0 = fold4(acc[0]), v1 = fold4(acc[1]), v2 = fold4(acc[2]), v3 = fold4(acc[3]);
    float v4 = fold4(acc[4]), v5 = fold4(acc[5]), v6 = fold4(acc[6]), v7 = fold4(acc[7]);
    float s0 = v0 + __shfl_xor(v0, 1, 8);
    float s1 = v1 + __shfl_xor(v1, 1, 8);
    float s2 = v2 + __shfl_xor(v2, 1, 8);
    float s3 = v3 + __shfl_xor(v3, 1, 8);
    float s4 = v4 + __shfl_xor(v4, 1, 8);
    float s5 = v5 + __shfl_xor(v5, 1, 8);
    float s6 = v6 + __shfl_xor(v6, 1, 8);
    float s7 = v7 + __shfl_xor(v7, 1, 8);
    const bool b0 = (j & 1);
    float t0 = b0 ? s1 : s0;
    float t1 = b0 ? s3 : s2;
    float t2 = b0 ? s5 : s4;
    float t3 = b0 ? s7 : s6;
    float p0 = t0 + __shfl_xor(t0, 2, 8);
    float p1 = t1 + __shfl_xor(t1, 2, 8);
    float p2 = t2 + __shfl_xor(t2, 2, 8);
    float p3 = t3 + __shfl_xor(t3, 2, 8);
    const bool b1 = (j & 2);
    float u0 = b1 ? p1 : p0;
    float u1 = b1 ? p3 : p2;
    float q0 = u0 + __shfl_xor(u0, 4, 8);
    float q1 = u1 + __shfl_xor(u1, 4, 8);
    return (j & 4) ? q1 : q0;
}

// 8-lane softmax + top2 epilogue for one token. (Verified R1-R5.)
__device__ __forceinline__ void softmax_top2(const float logit, const int j,
                                             const int token, float* __restrict__ out) {
    float m = logit;
#pragma unroll
    for (int s = 4; s; s >>= 1) m = fmaxf(m, __shfl_xor(m, s, 8));
    const float ex = expf(logit - m);
    float sum = ex;
#pragma unroll
    for (int s = 4; s; s >>= 1) sum += __shfl_xor(sum, s, 8);
    const float gate = ex / sum;

    out[65536 + token * NE + j] = gate;

    float g1 = gate; int e1 = j;
#pragma unroll
    for (int s = 4; s; s >>= 1) {
        const float og = __shfl_xor(g1, s, 8);
        const int   oe = __shfl_xor(e1, s, 8);
        if (og > g1 || (og == g1 && oe < e1)) { g1 = og; e1 = oe; }
    }
    float g2 = (j == e1) ? -INFINITY : gate; int e2 = j;
#pragma unroll
    for (int s = 4; s; s >>= 1) {
        const float og = __shfl_xor(g2, s, 8);
        const int   oe = __shfl_xor(e2, s, 8);
        if (og > g2 || (og == g2 && oe < e2)) { g2 = og; e2 = oe; }
    }
    if (j == 0) {
        out[token * 2 + 0]         = g1;
        out[token * 2 + 1]         = g2;
        out[32768 + token * 2 + 0] = (float)e1;
        out[32768 + token * 2 + 1] = (float)e2;
    }
}

// ---------------- Kernel 1: partial dots over one k-slice ----------------
// grid: 512 token-chunks x 8 k-slices = 4096 blocks, 256 threads.
// Each wave handles 8 tokens (lane = st*8+j), k-range = 256 floats.
__global__ __launch_bounds__(256, 6) void router_partial(
    const float* __restrict__ x,
    const float* __restrict__ W,
    float* __restrict__ part)
{
    __shared__ __align__(16) float sW8[NE * KSF];   // 8 KB

    const int t     = threadIdx.x;
    const int chunk = blockIdx.x >> 3;   // 0..511 (32 tokens each)
    const int ks    = blockIdx.x & 7;    // k-slice

    // stage W slice: W[e][ks*256 .. +256) -> sW8[e*256 ..). 512 float4s.
    {
        const float4* __restrict__ Wv = reinterpret_cast<const float4*>(W);
        float4* sWv = reinterpret_cast<float4*>(sW8);
#pragma unroll
        for (int i = 0; i < 2; ++i) {
            const int idx = i * 256 + t;        // 0..511
            const int e   = idx >> 6;           // 64 float4 per expert slice
            const int f4  = idx & 63;
            sWv[idx] = Wv[e * (DM / 4) + ks * (KSF / 4) + f4];
        }
    }
    __syncthreads();

    const int lane = t & 63;
    const int wave = t >> 6;
    const int j    = lane & 7;
    const int st   = lane >> 3;
    const int tok  = chunk * 32 + wave * 8 + st;

    const float* __restrict__ xp =
        x + (size_t)tok * DM + ks * KSF + (j << 2);

    float4 acc[NE];
#pragma unroll
    for (int e = 0; e < NE; ++e) acc[e] = make_float4(0.f, 0.f, 0.f, 0.f);

    // 8 iterations of 32 floats; depth-2 prefetch (TLP does the heavy lifting)
    float4 xa = *reinterpret_cast<const float4*>(xp);
#pragma unroll
    for (int it = 0; it < 8; ++it) {
        float4 xn;
        if (it < 7) xn = *reinterpret_cast<const float4*>(xp + ((it + 1) << 5));
        const float* wbase = &sW8[(it << 5) + (j << 2)];
#pragma unroll
        for (int e = 0; e < NE; ++e) {
            const float4 wv = *reinterpret_cast<const float4*>(wbase + e * KSF);
            acc[e].x = fmaf(xa.x, wv.x, acc[e].x);
            acc[e].y = fmaf(xa.y, wv.y, acc[e].y);
            acc[e].z = fmaf(xa.z, wv.z, acc[e].z);
            acc[e].w = fmaf(xa.w, wv.w, acc[e].w);
        }
        xa = xn;
    }

    const float p = reduce_scatter8(acc, j);
    // lanes of a wave write 64 contiguous floats -> one coalesced store
    part[(size_t)ks * PART_STRIDE + (size_t)tok * NE + j] = p;
}

// ---------------- Kernel 2: reduce slices + softmax + top2 ----------------
// 512 blocks x 256 threads; wave handles 8 tokens (lane = st*8+j).
__global__ __launch_bounds__(256) void router_final(
    const float* __restrict__ part,
    const float* __restrict__ b,
    float* __restrict__ out)
{
    const int t    = threadIdx.x;
    const int lane = t & 63;
    const int wave = t >> 6;
    const int j    = lane & 7;
    const int st   = lane >> 3;
    const int tok  = blockIdx.x * 32 + wave * 8 + st;

    const size_t base = (size_t)tok * NE + j;
    float s = 0.f;
#pragma unroll
    for (int ks = 0; ks < KS; ++ks)
        s += part[(size_t)ks * PART_STRIDE + base];

    const float logit = s + b[j];
    softmax_top2(logit, j, tok, out);
}

extern "C" void kernel_launch(void* const* d_in, const int* in_sizes, int n_in,
                              void* d_out, int out_size, void* d_ws, size_t ws_size,
                              hipStream_t stream) {
    const float* x = (const float*)d_in[0];
    const float* W = (const float*)d_in[1];
    const float* b = (const float*)d_in[2];
    float* out  = (float*)d_out;
    float* part = (float*)d_ws;   // 8 * 131072 floats = 4 MB, fully overwritten by K1

    router_partial<<<4096, 256, 0, stream>>>(x, W, part);
    router_final<<<512, 256, 0, stream>>>(part, b, out);
}